// Round 10
// baseline (586.800 us; speedup 1.0000x reference)
//
#include <hip/hip_runtime.h>
#include <math.h>
#include <string.h>

#define NLAT 91
#define NLON 180
#define NCH  64
#define KSZ  25
#define NW   9
#define HALF 4
#define NB   2
#define NPK  16     // channel packs of 4
#define CG   8      // blocks over channel packs
#define PPB  (NPK / CG)   // packs per block = 2
#define THREADS 384 // 2 unit-groups x 192
#define EUNIT 384   // entries per unit (multiple of 4)
#define ECAP  131072
#define UCAP  512   // pairs
#define XSCAP 2496  // float4 slots = 39936 B LDS (worst-case window ~2250)
#define LCAP  1024

// blob layout (host-built in ctor, one pinned H2D per call)
#define KOFF_OFF  0                     // 91*26*4 = 9464
#define ROW_OFF   9472                  // 91*9*16 = 13104
#define UNITS_OFF 22784                 // 512 pairs * 32 B = 16384
#define ENTS_OFF  39168                 // 256-aligned
#define BLOB_MAX  (ENTS_OFF + (size_t)ECAP * 8)

#ifndef M_PI
#define M_PI 3.14159265358979323846
#endif

typedef unsigned int u32;

// ---------------------------------------------------------------------------
// HOST (global ctor, outside graph capture): build the complete DISCO tables
// bit-compatibly with the numpy reference (glibc libm, exact IEEE op order,
// contraction off). Validated rounds 2-9 (absmax 1.5e-5). Every (t,k)
// segment is padded to a multiple of 4 -> the kernel's 4-way unrolled loop
// has no tails and 16B-aligned entry loads. Units are 384-entry windows,
// paired per-t (even count enforced by splitting the last unit).
// ---------------------------------------------------------------------------
static int build_tables(unsigned char* blob, int* ne_out)
{
#pragma clang fp contract(off)
    int*  koff  = (int*)(blob + KOFF_OFF);
    int4* rowi  = (int4*)(blob + ROW_OFF);
    u32*  units = (u32*)(blob + UNITS_OFF);
    u32*  ents  = (u32*)(blob + ENTS_OFF);   // pairs {off, f32 bits}

    static double sth[NLAT], cth[NLAT], cphv[NLON], sphv[NLON];
    for (int t = 0; t < NLAT; t++) {
        double th = (M_PI * (double)t) / 90.0;
        sth[t] = sin(th); cth[t] = cos(th);
    }
    for (int q = 0; q < NLON; q++) {
        double ph = (2.0 * M_PI * (double)q) / 180.0;
        cphv[q] = cos(ph); sphv[q] = sin(ph);
    }
    const double cutoff = (4.0 * M_PI) / 90.0;
    const double dr     = cutoff / 4.0;         // NR-1 = 4
    const double dphi   = (2.0 * M_PI) / 6.0;   // NPHI = 6

    static int   lcnt[KSZ];
    static int   loff_[KSZ][LCAP];
    static float lval[KSZ][LCAP];

    int ne = 0, nPairs = 0;
    for (int t = 0; t < NLAT; t++) {
        for (int k = 0; k < KSZ; k++) lcnt[k] = 0;
        int dqmin[NW], dqmax[NW];
        for (int w = 0; w < NW; w++) { dqmin[w] = 999; dqmax[w] = -999; }
        // pass 1: mask extents + per-k nonzero lists (w-major, dq-ascending)
        for (int w = 0; w < NW; w++) {
            int ti_raw = t - HALF + w;
            int valid = (ti_raw >= 0) && (ti_raw < NLAT);
            int ti = ti_raw < 0 ? 0 : (ti_raw > NLAT - 1 ? NLAT - 1 : ti_raw);
            for (int dq = -89; dq <= 90; dq++) {
                int q = dq < 0 ? dq + NLON : dq;
                double t1 = sth[t] * sth[ti];
                double t2 = t1 * cphv[q];
                double t3 = cth[t] * cth[ti];
                double zz = t2 + t3;
                if (zz > 1.0) zz = 1.0;
                if (zz < -1.0) zz = -1.0;
                double r = acos(zz);
                if (!(valid && (r <= cutoff))) continue;
                if (dq < dqmin[w]) dqmin[w] = dq;
                if (dq > dqmax[w]) dqmax[w] = dq;
                double xx = (cth[t] * sth[ti]) * cphv[q] - sth[t] * cth[ti];
                double yy = sth[ti] * sphv[q];
                double phi = atan2(yy, xx);
                { double m = fmod(phi, 2.0 * M_PI); if (m < 0.0) m += 2.0 * M_PI; phi = m; }
                double quad = sth[ti] * (M_PI / 90.0) * ((2.0 * M_PI) / 180.0);
                double v0 = fmax(0.0, 1.0 - r / dr);
                float f0 = (float)(v0 * quad);
                int pid = w * 512 + (dq + 128);
                if (f0 != 0.f && lcnt[0] < LCAP) {
                    loff_[0][lcnt[0]] = pid; lval[0][lcnt[0]] = f0; lcnt[0]++;
                }
                for (int ir = 1; ir < 5; ir++) {
                    double rad = fmax(0.0, 1.0 - fabs(r - ir * dr) / dr);
                    for (int ip = 0; ip < 6; ip++) {
                        double a = (phi - ip * dphi) + M_PI;
                        double m = fmod(a, 2.0 * M_PI);
                        if (m < 0.0) m += 2.0 * M_PI;
                        double dp = fabs(m - M_PI);
                        double ang = fmax(0.0, 1.0 - dp / dphi);
                        float f = (float)((rad * ang) * quad);
                        int k = 1 + (ir - 1) * 6 + ip;
                        if (f != 0.f && lcnt[k] < LCAP) {
                            loff_[k][lcnt[k]] = pid; lval[k][lcnt[k]] = f; lcnt[k]++;
                        }
                    }
                }
            }
        }
        // jagged LDS row layout
        int rb = 0, base[NW];
        for (int w = 0; w < NW; w++) {
            int len = (dqmin[w] <= dqmax[w]) ? (NLON + dqmax[w] - dqmin[w]) : 0;
            if (rb + len > XSCAP) len = XSCAP - rb;   // defensive
            int tw = t - HALF + w;
            int ti = tw < 0 ? 0 : (tw > NLAT - 1 ? NLAT - 1 : tw);
            base[w] = rb;
            rowi[t * NW + w] = make_int4(rb, len, (dqmin[w] <= dqmax[w]) ? dqmin[w] : 0, ti);
            rb += len;
        }
        // pass 2: emit entries, 4-padded per (t,k) segment
        int tBase = ne;
        for (int k = 0; k < KSZ; k++) {
            koff[t * (KSZ + 1) + k] = ne;
            for (int i = 0; i < lcnt[k] && ne < ECAP; i++) {
                int pid = loff_[k][i];
                int w = pid >> 9, dq = (pid & 511) - 128;
                u32 off = (u32)(base[w] + (dq - rowi[t * NW + w].z));
                ents[2 * ne] = off;
                float fv = lval[k][i];
                u32 fb; memcpy(&fb, &fv, 4);
                ents[2 * ne + 1] = fb;
                ne++;
            }
            while (((ne - koff[t * (KSZ + 1) + k]) & 3) && ne < ECAP) {
                ents[2 * ne] = 0; ents[2 * ne + 1] = 0; ne++;   // zero pad
            }
        }
        koff[t * (KSZ + 1) + KSZ] = ne;
        // per-t units (even count), then pair them
        int tu[128][2]; int ntu = 0;
        for (int e0 = tBase; e0 < ne && ntu < 127; e0 += EUNIT) {
            int e1 = e0 + EUNIT < ne ? e0 + EUNIT : ne;
            tu[ntu][0] = e0; tu[ntu][1] = e1; ntu++;
        }
        if (ntu & 1) {
            int a = tu[ntu - 1][0], b = tu[ntu - 1][1];
            int m = a + (((b - a) / 2 + 3) & ~3);
            if (m > b) m = b;
            tu[ntu - 1][1] = m;
            tu[ntu][0] = m; tu[ntu][1] = b;
            ntu++;   // second half may be empty (m==b) -> handled in kernel
        }
        for (int i = 0; i + 1 < ntu; i += 2) {
            // k-begin scan for each half
            int kb0 = 0, kb1 = 0;
            while (kb0 < KSZ && !(koff[t * (KSZ + 1) + kb0] <= tu[i][0] &&
                                  tu[i][0] < koff[t * (KSZ + 1) + kb0 + 1])) kb0++;
            while (kb1 < KSZ && !(koff[t * (KSZ + 1) + kb1] <= tu[i + 1][0] &&
                                  tu[i + 1][0] < koff[t * (KSZ + 1) + kb1 + 1])) kb1++;
            if (nPairs < UCAP) {
                u32* up = units + nPairs * 8;
                up[0] = (u32)t;
                up[1] = (u32)tu[i][0];     up[2] = (u32)tu[i][1];     up[3] = (u32)kb0;
                up[4] = (u32)tu[i + 1][0]; up[5] = (u32)tu[i + 1][1]; up[6] = (u32)kb1;
                up[7] = 0;
                nPairs++;
            }
        }
    }
    *ne_out = ne;
    return nPairs;
}

// Global init at dlopen: build once, stage in pinned memory for fast replay.
struct GInit {
    unsigned char* blob;
    int nu, ne;
    size_t bytes;
    GInit() {
        static unsigned char storage[BLOB_MAX];
        nu = build_tables(storage, &ne);
        bytes = ENTS_OFF + (size_t)ne * 8;
        unsigned char* p = nullptr;
        if (hipHostMalloc((void**)&p, bytes) == hipSuccess && p) {
            memcpy(p, storage, bytes);
            blob = p;
        } else {
            blob = storage;   // pageable fallback
        }
    }
};
static GInit g_init;

// ---------------------------------------------------------------------------
// pack x [b][c][t][p] -> xp4[((b*16+cp)*91+t)*180+p] float4 of 4 channels.
// ---------------------------------------------------------------------------
__global__ __launch_bounds__(192) void pack_x(const float* __restrict__ x,
                                              float4* __restrict__ xp4)
{
    int t = blockIdx.x, cp = blockIdx.y, b = blockIdx.z;
    int p = threadIdx.x;
    if (p >= NLON) return;
    int c0 = cp * 4;
    float4 v;
    v.x = x[((size_t)(b * NCH + c0 + 0) * NLAT + t) * NLON + p];
    v.y = x[((size_t)(b * NCH + c0 + 1) * NLAT + t) * NLON + p];
    v.z = x[((size_t)(b * NCH + c0 + 2) * NLAT + t) * NLON + p];
    v.w = x[((size_t)(b * NCH + c0 + 3) * NLAT + t) * NLON + p];
    xp4[((size_t)(b * NPK + cp) * NLAT + t) * NLON + p] = v;
}

// ---------------------------------------------------------------------------
// weights [o][c][k] -> wt2[(cp*25+k)*64+o] float4 over the pack's 4 c.
// ---------------------------------------------------------------------------
__global__ void pack_w(const float* __restrict__ wgt, float4* __restrict__ wt2)
{
    int i = blockIdx.x * blockDim.x + threadIdx.x;
    if (i >= NPK * KSZ * NCH) return;
    int cp = i / (KSZ * NCH);
    int rem = i - cp * (KSZ * NCH);
    int k = rem / NCH;
    int o = rem - k * NCH;
    float4 v;
    v.x = wgt[((size_t)o * NCH + cp * 4 + 0) * KSZ + k];
    v.y = wgt[((size_t)o * NCH + cp * 4 + 1) * KSZ + k];
    v.z = wgt[((size_t)o * NCH + cp * 4 + 2) * KSZ + k];
    v.w = wgt[((size_t)o * NCH + cp * 4 + 3) * KSZ + k];
    wt2[i] = v;
}

// ---------------------------------------------------------------------------
// Main fused kernel. Block = (unit-PAIR, cg, b); 384 threads = 2 groups of
// 192 (6 waves). Both groups share the same latitude t and the same 39.9KB
// jagged LDS window -> double the waves per byte of LDS vs round 9.
// Group g walks its own entry range with the 4-way unrolled gather-FMA loop;
// per-k flush into acc[64]; atomic epilogue.
// ---------------------------------------------------------------------------
__global__ __launch_bounds__(THREADS, 6) void disco_fused(
    const float4* __restrict__ xp4, const float4* __restrict__ wt2,
    const uint2* __restrict__ ents, const int* __restrict__ koffG,
    const int4* __restrict__ rowinfoG, const uint4* __restrict__ units,
    float* __restrict__ out)
{
    const uint4 ua = units[(size_t)blockIdx.x * 2];
    const uint4 ub = units[(size_t)blockIdx.x * 2 + 1];
    int tid = threadIdx.x;
    bool grpB = (tid >= 192);                      // wave-uniform (192 = 3 waves)
    int t    = __builtin_amdgcn_readfirstlane((int)ua.x);
    int eBeg = __builtin_amdgcn_readfirstlane((int)(grpB ? ub.x : ua.y));
    int eEnd = __builtin_amdgcn_readfirstlane((int)(grpB ? ub.y : ua.z));
    int kBeg = __builtin_amdgcn_readfirstlane((int)(grpB ? ub.z : ua.w));
    int cg = blockIdx.y, b = blockIdx.z;
    int lid = grpB ? tid - 192 : tid;
    int p = lid < NLON ? lid : NLON - 1;
    bool act = lid < NLON;
    bool hasWork = eBeg < eEnd;

    __shared__ float4 xs[XSCAP];    // 39936 B -> 4 blocks/CU
    const int* ko = koffG + t * (KSZ + 1);
    const int4* ri9 = rowinfoG + t * NW;

    float acc[NCH];
#pragma unroll
    for (int o = 0; o < NCH; o++) acc[o] = 0.f;

    for (int pk = 0; pk < PPB; pk++) {
        int cp = cg * PPB + pk;
        __syncthreads();
#pragma unroll
        for (int w = 0; w < NW; w++) {
            int4 ri = ri9[w];                       // {base, len, dqmin, ti}
            const float4* src = xp4 + ((size_t)(b * NPK + cp) * NLAT + ri.w) * NLON;
            for (int j = tid; j < ri.y; j += THREADS) {
                int s = j + ri.z;
                if (s < 0) s += NLON;
                if (s >= NLON) s -= NLON;
                xs[ri.x + j] = src[s];
            }
        }
        __syncthreads();

        if (hasWork) {
            int e = eBeg, k = kBeg;
            while (e < eEnd) {
                int kend = ko[k + 1];
                if (kend > eEnd) kend = eEnd;
                if (kend > e) {
                    float z00=0.f,z01=0.f,z02=0.f,z03=0.f;
                    float z10=0.f,z11=0.f,z12=0.f,z13=0.f;
                    float z20=0.f,z21=0.f,z22=0.f,z23=0.f;
                    float z30=0.f,z31=0.f,z32=0.f,z33=0.f;
                    for (; e < kend; e += 4) {          // segments 4-padded: no tail
                        const uint4* e4 = (const uint4*)(ents + e);
                        uint4 A = e4[0], B = e4[1];
                        float4 x0 = xs[A.x + p];
                        float4 x1 = xs[A.z + p];
                        float4 x2 = xs[B.x + p];
                        float4 x3 = xs[B.z + p];
                        float v0 = __uint_as_float(A.y), v1 = __uint_as_float(A.w);
                        float v2 = __uint_as_float(B.y), v3 = __uint_as_float(B.w);
                        z00 = fmaf(v0, x0.x, z00); z01 = fmaf(v0, x0.y, z01);
                        z02 = fmaf(v0, x0.z, z02); z03 = fmaf(v0, x0.w, z03);
                        z10 = fmaf(v1, x1.x, z10); z11 = fmaf(v1, x1.y, z11);
                        z12 = fmaf(v1, x1.z, z12); z13 = fmaf(v1, x1.w, z13);
                        z20 = fmaf(v2, x2.x, z20); z21 = fmaf(v2, x2.y, z21);
                        z22 = fmaf(v2, x2.z, z22); z23 = fmaf(v2, x2.w, z23);
                        z30 = fmaf(v3, x3.x, z30); z31 = fmaf(v3, x3.y, z31);
                        z32 = fmaf(v3, x3.z, z32); z33 = fmaf(v3, x3.w, z33);
                    }
                    float zc0 = (z00 + z10) + (z20 + z30);
                    float zc1 = (z01 + z11) + (z21 + z31);
                    float zc2 = (z02 + z12) + (z22 + z32);
                    float zc3 = (z03 + z13) + (z23 + z33);
                    const float4* wk = wt2 + ((size_t)cp * KSZ + k) * NCH;
#pragma unroll
                    for (int o = 0; o < NCH; o++) {
                        float4 w4 = wk[o];
                        acc[o] = fmaf(w4.w, zc3, fmaf(w4.z, zc2,
                                 fmaf(w4.y, zc1, fmaf(w4.x, zc0, acc[o]))));
                    }
                }
                k++;
                if (k >= KSZ) break;
            }
        }
    }

    if (act && hasWork) {
        float* op = out + ((size_t)b * NCH * NLAT * NLON) + (size_t)t * NLON + p;
#pragma unroll
        for (int o = 0; o < NCH; o++)
            atomicAdd(op + (size_t)o * (NLAT * NLON), acc[o]);
    }
}

extern "C" void kernel_launch(void* const* d_in, const int* in_sizes, int n_in,
                              void* d_out, int out_size, void* d_ws, size_t ws_size,
                              hipStream_t stream)
{
    const float* x   = (const float*)d_in[0];
    const float* wgt = (const float*)d_in[1];
    char* ws = (char*)d_ws;

    size_t cur = 0;
    auto alloc = [&](size_t bytes) { size_t o = cur; cur = (cur + bytes + 255) & ~(size_t)255; return o; };
    size_t blob_off = alloc(BLOB_MAX);                                // ~1.09 MB
    size_t xp4_off  = alloc((size_t)NB * NPK * NLAT * NLON * 16);     // 8.4 MB
    size_t wt2_off  = alloc((size_t)NPK * KSZ * NCH * 16);            // 400 KB

    unsigned char* d_blob = (unsigned char*)(ws + blob_off);
    float4*        xp4    = (float4*)(ws + xp4_off);
    float4*        wt2    = (float4*)(ws + wt2_off);

    hipMemcpyAsync(d_blob, g_init.blob, g_init.bytes, hipMemcpyHostToDevice, stream);
    pack_x<<<dim3(NLAT, NPK, NB), 192, 0, stream>>>(x, xp4);
    pack_w<<<(NPK * KSZ * NCH + 255) / 256, 256, 0, stream>>>(wgt, wt2);
    hipMemsetAsync(d_out, 0, (size_t)out_size * 4, stream);

    const uint2* entsD = (const uint2*)(d_blob + ENTS_OFF);
    const int*   koffD = (const int*)(d_blob + KOFF_OFF);
    const int4*  rowD  = (const int4*)(d_blob + ROW_OFF);
    const uint4* unitD = (const uint4*)(d_blob + UNITS_OFF);

    disco_fused<<<dim3(g_init.nu, CG, NB), THREADS, 0, stream>>>(
        xp4, wt2, entsD, koffD, rowD, unitD, (float*)d_out);
}

// Round 11
// 425.954 us; speedup vs baseline: 1.3776x; 1.3776x over previous
//
#include <hip/hip_runtime.h>
#include <math.h>
#include <string.h>

#define NLAT 91
#define NLON 180
#define NCH  64
#define KSZ  25
#define NW   9
#define HALF 4
#define NB   2
#define NPK  16     // channel packs of 4
#define CG   8      // blocks over channel packs
#define PPB  (NPK / CG)   // packs per block = 2
#define THREADS 384 // 2 unit-groups x 192
#define EUNIT 384   // entries per unit (multiple of 4)
#define ECAP  131072
#define UCAP  512   // pairs
#define XSCAP 2496  // float4 slots = 39936 B LDS (worst-case window ~2250)
#define LCAP  1024

// blob layout (host-built in ctor, one pinned H2D per call)
#define KOFF_OFF  0                     // 91*26*4 = 9464
#define ROW_OFF   9472                  // 91*9*16 = 13104
#define UNITS_OFF 22784                 // 512 pairs * 32 B = 16384
#define ENTS_OFF  39168                 // 256-aligned
#define BLOB_MAX  (ENTS_OFF + (size_t)ECAP * 8)

#ifndef M_PI
#define M_PI 3.14159265358979323846
#endif

typedef unsigned int u32;

// ---------------------------------------------------------------------------
// HOST (global ctor, outside graph capture): build the complete DISCO tables
// bit-compatibly with the numpy reference (glibc libm, exact IEEE op order,
// contraction off). Validated rounds 2-10 (absmax 1.5e-5). Every (t,k)
// segment is padded to a multiple of 4 -> the kernel's 4-way unrolled loop
// has no tails and 16B-aligned entry loads. Units are 384-entry windows,
// paired per-t (even count enforced by splitting the last unit).
// ---------------------------------------------------------------------------
static int build_tables(unsigned char* blob, int* ne_out)
{
#pragma clang fp contract(off)
    int*  koff  = (int*)(blob + KOFF_OFF);
    int4* rowi  = (int4*)(blob + ROW_OFF);
    u32*  units = (u32*)(blob + UNITS_OFF);
    u32*  ents  = (u32*)(blob + ENTS_OFF);   // pairs {off, f32 bits}

    static double sth[NLAT], cth[NLAT], cphv[NLON], sphv[NLON];
    for (int t = 0; t < NLAT; t++) {
        double th = (M_PI * (double)t) / 90.0;
        sth[t] = sin(th); cth[t] = cos(th);
    }
    for (int q = 0; q < NLON; q++) {
        double ph = (2.0 * M_PI * (double)q) / 180.0;
        cphv[q] = cos(ph); sphv[q] = sin(ph);
    }
    const double cutoff = (4.0 * M_PI) / 90.0;
    const double dr     = cutoff / 4.0;         // NR-1 = 4
    const double dphi   = (2.0 * M_PI) / 6.0;   // NPHI = 6

    static int   lcnt[KSZ];
    static int   loff_[KSZ][LCAP];
    static float lval[KSZ][LCAP];

    int ne = 0, nPairs = 0;
    for (int t = 0; t < NLAT; t++) {
        for (int k = 0; k < KSZ; k++) lcnt[k] = 0;
        int dqmin[NW], dqmax[NW];
        for (int w = 0; w < NW; w++) { dqmin[w] = 999; dqmax[w] = -999; }
        // pass 1: mask extents + per-k nonzero lists (w-major, dq-ascending)
        for (int w = 0; w < NW; w++) {
            int ti_raw = t - HALF + w;
            int valid = (ti_raw >= 0) && (ti_raw < NLAT);
            int ti = ti_raw < 0 ? 0 : (ti_raw > NLAT - 1 ? NLAT - 1 : ti_raw);
            for (int dq = -89; dq <= 90; dq++) {
                int q = dq < 0 ? dq + NLON : dq;
                double t1 = sth[t] * sth[ti];
                double t2 = t1 * cphv[q];
                double t3 = cth[t] * cth[ti];
                double zz = t2 + t3;
                if (zz > 1.0) zz = 1.0;
                if (zz < -1.0) zz = -1.0;
                double r = acos(zz);
                if (!(valid && (r <= cutoff))) continue;
                if (dq < dqmin[w]) dqmin[w] = dq;
                if (dq > dqmax[w]) dqmax[w] = dq;
                double xx = (cth[t] * sth[ti]) * cphv[q] - sth[t] * cth[ti];
                double yy = sth[ti] * sphv[q];
                double phi = atan2(yy, xx);
                { double m = fmod(phi, 2.0 * M_PI); if (m < 0.0) m += 2.0 * M_PI; phi = m; }
                double quad = sth[ti] * (M_PI / 90.0) * ((2.0 * M_PI) / 180.0);
                double v0 = fmax(0.0, 1.0 - r / dr);
                float f0 = (float)(v0 * quad);
                int pid = w * 512 + (dq + 128);
                if (f0 != 0.f && lcnt[0] < LCAP) {
                    loff_[0][lcnt[0]] = pid; lval[0][lcnt[0]] = f0; lcnt[0]++;
                }
                for (int ir = 1; ir < 5; ir++) {
                    double rad = fmax(0.0, 1.0 - fabs(r - ir * dr) / dr);
                    for (int ip = 0; ip < 6; ip++) {
                        double a = (phi - ip * dphi) + M_PI;
                        double m = fmod(a, 2.0 * M_PI);
                        if (m < 0.0) m += 2.0 * M_PI;
                        double dp = fabs(m - M_PI);
                        double ang = fmax(0.0, 1.0 - dp / dphi);
                        float f = (float)((rad * ang) * quad);
                        int k = 1 + (ir - 1) * 6 + ip;
                        if (f != 0.f && lcnt[k] < LCAP) {
                            loff_[k][lcnt[k]] = pid; lval[k][lcnt[k]] = f; lcnt[k]++;
                        }
                    }
                }
            }
        }
        // jagged LDS row layout
        int rb = 0, base[NW];
        for (int w = 0; w < NW; w++) {
            int len = (dqmin[w] <= dqmax[w]) ? (NLON + dqmax[w] - dqmin[w]) : 0;
            if (rb + len > XSCAP) len = XSCAP - rb;   // defensive
            int tw = t - HALF + w;
            int ti = tw < 0 ? 0 : (tw > NLAT - 1 ? NLAT - 1 : tw);
            base[w] = rb;
            rowi[t * NW + w] = make_int4(rb, len, (dqmin[w] <= dqmax[w]) ? dqmin[w] : 0, ti);
            rb += len;
        }
        // pass 2: emit entries, 4-padded per (t,k) segment
        int tBase = ne;
        for (int k = 0; k < KSZ; k++) {
            koff[t * (KSZ + 1) + k] = ne;
            for (int i = 0; i < lcnt[k] && ne < ECAP; i++) {
                int pid = loff_[k][i];
                int w = pid >> 9, dq = (pid & 511) - 128;
                u32 off = (u32)(base[w] + (dq - rowi[t * NW + w].z));
                ents[2 * ne] = off;
                float fv = lval[k][i];
                u32 fb; memcpy(&fb, &fv, 4);
                ents[2 * ne + 1] = fb;
                ne++;
            }
            while (((ne - koff[t * (KSZ + 1) + k]) & 3) && ne < ECAP) {
                ents[2 * ne] = 0; ents[2 * ne + 1] = 0; ne++;   // zero pad
            }
        }
        koff[t * (KSZ + 1) + KSZ] = ne;
        // per-t units (even count), then pair them
        int tu[128][2]; int ntu = 0;
        for (int e0 = tBase; e0 < ne && ntu < 127; e0 += EUNIT) {
            int e1 = e0 + EUNIT < ne ? e0 + EUNIT : ne;
            tu[ntu][0] = e0; tu[ntu][1] = e1; ntu++;
        }
        if (ntu & 1) {
            int a = tu[ntu - 1][0], b = tu[ntu - 1][1];
            int m = a + (((b - a) / 2 + 3) & ~3);
            if (m > b) m = b;
            tu[ntu - 1][1] = m;
            tu[ntu][0] = m; tu[ntu][1] = b;
            ntu++;   // second half may be empty (m==b) -> handled in kernel
        }
        for (int i = 0; i + 1 < ntu; i += 2) {
            int kb0 = 0, kb1 = 0;
            while (kb0 < KSZ && !(koff[t * (KSZ + 1) + kb0] <= tu[i][0] &&
                                  tu[i][0] < koff[t * (KSZ + 1) + kb0 + 1])) kb0++;
            while (kb1 < KSZ && !(koff[t * (KSZ + 1) + kb1] <= tu[i + 1][0] &&
                                  tu[i + 1][0] < koff[t * (KSZ + 1) + kb1 + 1])) kb1++;
            if (nPairs < UCAP) {
                u32* up = units + nPairs * 8;
                up[0] = (u32)t;
                up[1] = (u32)tu[i][0];     up[2] = (u32)tu[i][1];     up[3] = (u32)kb0;
                up[4] = (u32)tu[i + 1][0]; up[5] = (u32)tu[i + 1][1]; up[6] = (u32)kb1;
                up[7] = 0;
                nPairs++;
            }
        }
    }
    *ne_out = ne;
    return nPairs;
}

// Global init at dlopen: build once, stage in pinned memory for fast replay.
struct GInit {
    unsigned char* blob;
    int nu, ne;
    size_t bytes;
    GInit() {
        static unsigned char storage[BLOB_MAX];
        nu = build_tables(storage, &ne);
        bytes = ENTS_OFF + (size_t)ne * 8;
        unsigned char* p = nullptr;
        if (hipHostMalloc((void**)&p, bytes) == hipSuccess && p) {
            memcpy(p, storage, bytes);
            blob = p;
        } else {
            blob = storage;   // pageable fallback
        }
    }
};
static GInit g_init;

// ---------------------------------------------------------------------------
// pack x [b][c][t][p] -> xp4[((b*16+cp)*91+t)*180+p] float4 of 4 channels.
// ---------------------------------------------------------------------------
__global__ __launch_bounds__(192) void pack_x(const float* __restrict__ x,
                                              float4* __restrict__ xp4)
{
    int t = blockIdx.x, cp = blockIdx.y, b = blockIdx.z;
    int p = threadIdx.x;
    if (p >= NLON) return;
    int c0 = cp * 4;
    float4 v;
    v.x = x[((size_t)(b * NCH + c0 + 0) * NLAT + t) * NLON + p];
    v.y = x[((size_t)(b * NCH + c0 + 1) * NLAT + t) * NLON + p];
    v.z = x[((size_t)(b * NCH + c0 + 2) * NLAT + t) * NLON + p];
    v.w = x[((size_t)(b * NCH + c0 + 3) * NLAT + t) * NLON + p];
    xp4[((size_t)(b * NPK + cp) * NLAT + t) * NLON + p] = v;
}

// ---------------------------------------------------------------------------
// weights [o][c][k] -> wt2[(cp*25+k)*64+o] float4 over the pack's 4 c.
// ---------------------------------------------------------------------------
__global__ void pack_w(const float* __restrict__ wgt, float4* __restrict__ wt2)
{
    int i = blockIdx.x * blockDim.x + threadIdx.x;
    if (i >= NPK * KSZ * NCH) return;
    int cp = i / (KSZ * NCH);
    int rem = i - cp * (KSZ * NCH);
    int k = rem / NCH;
    int o = rem - k * NCH;
    float4 v;
    v.x = wgt[((size_t)o * NCH + cp * 4 + 0) * KSZ + k];
    v.y = wgt[((size_t)o * NCH + cp * 4 + 1) * KSZ + k];
    v.z = wgt[((size_t)o * NCH + cp * 4 + 2) * KSZ + k];
    v.w = wgt[((size_t)o * NCH + cp * 4 + 3) * KSZ + k];
    wt2[i] = v;
}

// ---------------------------------------------------------------------------
// Main fused kernel. Block = (unit-PAIR, cg, b); 384 threads = 2 groups of
// 192 (3 waves each) sharing one latitude t and one 39.9KB jagged LDS window.
// __launch_bounds__(384,4): VGPR cap 128 >= ~110 footprint -> NO SPILL
// (round 10's (384,6) cap=85 spilled acc[64] to scratch: 1 GB WRITE_SIZE).
// Inner loop: 4 independent ds_read_b128 in flight, accumulated into 4
// per-channel FMA chains (z trimmed 16->4 regs). Per-k flush into acc[64].
// ---------------------------------------------------------------------------
__global__ __launch_bounds__(THREADS, 4) void disco_fused(
    const float4* __restrict__ xp4, const float4* __restrict__ wt2,
    const uint2* __restrict__ ents, const int* __restrict__ koffG,
    const int4* __restrict__ rowinfoG, const uint4* __restrict__ units,
    float* __restrict__ out)
{
    const uint4 ua = units[(size_t)blockIdx.x * 2];
    const uint4 ub = units[(size_t)blockIdx.x * 2 + 1];
    int tid = threadIdx.x;
    bool grpB = (tid >= 192);                      // wave-uniform (192 = 3 waves)
    int t    = __builtin_amdgcn_readfirstlane((int)ua.x);
    int eBeg = __builtin_amdgcn_readfirstlane((int)(grpB ? ub.x : ua.y));
    int eEnd = __builtin_amdgcn_readfirstlane((int)(grpB ? ub.y : ua.z));
    int kBeg = __builtin_amdgcn_readfirstlane((int)(grpB ? ub.z : ua.w));
    int cg = blockIdx.y, b = blockIdx.z;
    int lid = grpB ? tid - 192 : tid;
    int p = lid < NLON ? lid : NLON - 1;
    bool act = lid < NLON;
    bool hasWork = eBeg < eEnd;

    __shared__ float4 xs[XSCAP];    // 39936 B
    const int* ko = koffG + t * (KSZ + 1);
    const int4* ri9 = rowinfoG + t * NW;

    float acc[NCH];
#pragma unroll
    for (int o = 0; o < NCH; o++) acc[o] = 0.f;

    for (int pk = 0; pk < PPB; pk++) {
        int cp = cg * PPB + pk;
        __syncthreads();
#pragma unroll
        for (int w = 0; w < NW; w++) {
            int4 ri = ri9[w];                       // {base, len, dqmin, ti}
            const float4* src = xp4 + ((size_t)(b * NPK + cp) * NLAT + ri.w) * NLON;
            for (int j = tid; j < ri.y; j += THREADS) {
                int s = j + ri.z;
                if (s < 0) s += NLON;
                if (s >= NLON) s -= NLON;
                xs[ri.x + j] = src[s];
            }
        }
        __syncthreads();

        if (hasWork) {
            int e = eBeg, k = kBeg;
            while (e < eEnd) {
                int kend = ko[k + 1];
                if (kend > eEnd) kend = eEnd;
                if (kend > e) {
                    float z0 = 0.f, z1 = 0.f, z2 = 0.f, z3 = 0.f;
                    for (; e < kend; e += 4) {          // segments 4-padded: no tail
                        const uint4* e4 = (const uint4*)(ents + e);
                        uint4 A = e4[0], B = e4[1];
                        float4 x0 = xs[A.x + p];        // 4 independent b128 reads
                        float4 x1 = xs[A.z + p];
                        float4 x2 = xs[B.x + p];
                        float4 x3 = xs[B.z + p];
                        float v0 = __uint_as_float(A.y), v1 = __uint_as_float(A.w);
                        float v2 = __uint_as_float(B.y), v3 = __uint_as_float(B.w);
                        z0 = fmaf(v0, x0.x, z0); z1 = fmaf(v0, x0.y, z1);
                        z2 = fmaf(v0, x0.z, z2); z3 = fmaf(v0, x0.w, z3);
                        z0 = fmaf(v1, x1.x, z0); z1 = fmaf(v1, x1.y, z1);
                        z2 = fmaf(v1, x1.z, z2); z3 = fmaf(v1, x1.w, z3);
                        z0 = fmaf(v2, x2.x, z0); z1 = fmaf(v2, x2.y, z1);
                        z2 = fmaf(v2, x2.z, z2); z3 = fmaf(v2, x2.w, z3);
                        z0 = fmaf(v3, x3.x, z0); z1 = fmaf(v3, x3.y, z1);
                        z2 = fmaf(v3, x3.z, z2); z3 = fmaf(v3, x3.w, z3);
                    }
                    const float4* wk = wt2 + ((size_t)cp * KSZ + k) * NCH;
#pragma unroll
                    for (int o = 0; o < NCH; o++) {
                        float4 w4 = wk[o];
                        acc[o] = fmaf(w4.w, z3, fmaf(w4.z, z2,
                                 fmaf(w4.y, z1, fmaf(w4.x, z0, acc[o]))));
                    }
                }
                k++;
                if (k >= KSZ) break;
            }
        }
    }

    if (act && hasWork) {
        float* op = out + ((size_t)b * NCH * NLAT * NLON) + (size_t)t * NLON + p;
#pragma unroll
        for (int o = 0; o < NCH; o++)
            atomicAdd(op + (size_t)o * (NLAT * NLON), acc[o]);
    }
}

extern "C" void kernel_launch(void* const* d_in, const int* in_sizes, int n_in,
                              void* d_out, int out_size, void* d_ws, size_t ws_size,
                              hipStream_t stream)
{
    const float* x   = (const float*)d_in[0];
    const float* wgt = (const float*)d_in[1];
    char* ws = (char*)d_ws;

    size_t cur = 0;
    auto alloc = [&](size_t bytes) { size_t o = cur; cur = (cur + bytes + 255) & ~(size_t)255; return o; };
    size_t blob_off = alloc(BLOB_MAX);                                // ~1.09 MB
    size_t xp4_off  = alloc((size_t)NB * NPK * NLAT * NLON * 16);     // 8.4 MB
    size_t wt2_off  = alloc((size_t)NPK * KSZ * NCH * 16);            // 400 KB

    unsigned char* d_blob = (unsigned char*)(ws + blob_off);
    float4*        xp4    = (float4*)(ws + xp4_off);
    float4*        wt2    = (float4*)(ws + wt2_off);

    hipMemcpyAsync(d_blob, g_init.blob, g_init.bytes, hipMemcpyHostToDevice, stream);
    pack_x<<<dim3(NLAT, NPK, NB), 192, 0, stream>>>(x, xp4);
    pack_w<<<(NPK * KSZ * NCH + 255) / 256, 256, 0, stream>>>(wgt, wt2);
    hipMemsetAsync(d_out, 0, (size_t)out_size * 4, stream);

    const uint2* entsD = (const uint2*)(d_blob + ENTS_OFF);
    const int*   koffD = (const int*)(d_blob + KOFF_OFF);
    const int4*  rowD  = (const int4*)(d_blob + ROW_OFF);
    const uint4* unitD = (const uint4*)(d_blob + UNITS_OFF);

    disco_fused<<<dim3(g_init.nu, CG, NB), THREADS, 0, stream>>>(
        xp4, wt2, entsD, koffD, rowD, unitD, (float*)d_out);
}